// Round 6
// baseline (958.319 us; speedup 1.0000x reference)
//
#include <hip/hip_runtime.h>

// MoE FFN: D=1024, H=4096, E=8, top-2, T=4096 tokens, fp32 in/out, bf16 MFMA compute.
// R8: STRUCTURE round. R3/R4/R6/R7 proved the 128²/2-barrier K-loop is pinned
// at ~400 TF (MfmaUtil 14-18%) regardless of pipeline depth, split-K, traffic,
// or occupancy -> the per-K-step {stage+vmcnt+barrier} overhead dominates
// (m233: ~72% of a 2-phase loop). Fix: 256x256 tile, BK=64, 8 waves, 128KB
// double-buffered LDS -> 64 MFMA/wave per barrier-pair (4x the compute per
// overhead unit). Schedule per K-tile: issue stage(j+1) FIRST (into the buffer
// sealed by the previous barrier), then ds_read+MFMA, then one vmcnt(0)+barrier.
// LDS keeps the verified zero-conflict chunk swizzle per 32-K subtile.
// Merged shared+expert grouped dispatch, expert ranges padded to 256.

#define T_TOKENS 4096
#define DM 1024
#define HID 4096
#define NE 8
#define MT_SH2 (T_TOKENS / 256)                  // 16 shared m-tiles (256-rows)
#define SLOTS_MAX (2 * T_TOKENS + 256 * NE)      // 10240 padded expert slots max
#define MT_EX2 (SLOTS_MAX / 256)                 // 40 expert m-tiles max

typedef __attribute__((ext_vector_type(8))) short short8;
typedef __attribute__((ext_vector_type(4))) float f32x4;
typedef unsigned short u16;

__device__ __forceinline__ u16 f2b(float f) {
    unsigned u = __builtin_bit_cast(unsigned, f);
    u += 0x7FFFu + ((u >> 16) & 1u);   // round-to-nearest-even
    return (u16)(u >> 16);
}

__device__ __forceinline__ uint4 load8(const u16* p) {
    return *(const uint4*)p;           // 8 bf16 = 16 B
}
__device__ __forceinline__ uint4 load8(const float* p) {
    const float4* q = (const float4*)p;
    float4 a = q[0], b = q[1];
    uint4 r;
    r.x = (unsigned)f2b(a.x) | ((unsigned)f2b(a.y) << 16);
    r.y = (unsigned)f2b(a.z) | ((unsigned)f2b(a.w) << 16);
    r.z = (unsigned)f2b(b.x) | ((unsigned)f2b(b.y) << 16);
    r.w = (unsigned)f2b(b.z) | ((unsigned)f2b(b.w) << 16);
    return r;
}

// async 16B global -> LDS (wave-uniform lds base + lane*16)
__device__ __forceinline__ void gld16(const u16* g, u16* lds) {
    __builtin_amdgcn_global_load_lds(
        (const __attribute__((address_space(1))) void*)g,
        (__attribute__((address_space(3))) void*)lds, 16, 0, 0);
}

// ---- fused fp32 -> bf16 conversion of all tensors --------------------------
constexpr long CN0 = (long)T_TOKENS * DM;        // x
constexpr long CN1 = CN0 + (long)HID * DM;       // sw1
constexpr long CN2 = CN1 + (long)DM * HID;       // sw2
constexpr long CN3 = CN2 + (long)NE * HID * DM;  // ew1
constexpr long CN4 = CN3 + (long)NE * DM * HID;  // ew2

template<bool FULL>
__global__ __launch_bounds__(256) void cvt_all_kernel(
    const float* __restrict__ x,  const float* __restrict__ sw1,
    const float* __restrict__ sw2, const float* __restrict__ ew1,
    const float* __restrict__ ew2,
    u16* __restrict__ xb, u16* __restrict__ sw1b, u16* __restrict__ sw2b,
    u16* __restrict__ ew1b, u16* __restrict__ ew2b) {
    long i = ((long)blockIdx.x * 256 + threadIdx.x) * 8;
    const float* s; u16* d; long base;
    if (i < CN0)      { s = x;   d = xb;   base = 0;   }
    else if (i < CN1) { s = sw1; d = sw1b; base = CN0; }
    else if (i < CN2) { s = sw2; d = sw2b; base = CN1; }
    else if (FULL && i < CN3) { s = ew1; d = ew1b; base = CN2; }
    else if (FULL && i < CN4) { s = ew2; d = ew2b; base = CN3; }
    else return;
    long j = i - base;
    *(uint4*)(d + j) = load8(s + j);
}

// ---- gating (fp32: bf16 logits would flip near-tie expert picks) -----------
__global__ __launch_bounds__(256) void gate_kernel(const float* __restrict__ x,
                                                   const float* __restrict__ gw,
                                                   int* __restrict__ cnt,
                                                   int2* __restrict__ topidx,
                                                   float2* __restrict__ topg) {
    int t = blockIdx.x * 4 + (threadIdx.x >> 6);
    int lane = threadIdx.x & 63;
    const float* xr = x + (long)t * DM;
    float s[NE];
#pragma unroll
    for (int e = 0; e < NE; e++) s[e] = 0.f;
    for (int i = lane; i < DM; i += 64) {
        float xv = xr[i];
#pragma unroll
        for (int e = 0; e < NE; e++) s[e] += xv * gw[e * DM + i];
    }
#pragma unroll
    for (int e = 0; e < NE; e++)
        for (int o = 32; o > 0; o >>= 1) s[e] += __shfl_down(s[e], o);
    if (lane == 0) {
        int i0 = 0; float l0 = s[0];
#pragma unroll
        for (int e = 1; e < NE; e++) if (s[e] > l0) { l0 = s[e]; i0 = e; }
        int i1 = -1; float l1 = -1e30f;
#pragma unroll
        for (int e = 0; e < NE; e++) if (e != i0 && s[e] > l1) { l1 = s[e]; i1 = e; }
        float e1 = __expf(l1 - l0);
        float inv = 1.f / (1.f + e1);
        topidx[t] = make_int2(i0, i1);
        topg[t]   = make_float2(inv, e1 * inv);
        atomicAdd(&cnt[i0], 1);
        atomicAdd(&cnt[i1], 1);
    }
}

// offs padded to 256-aligned ranges: every expert m-tile is FULL (padding
// slots have tok=0/gate=0 from the memset -> contribute exactly 0 in L2).
__global__ void prefix_kernel(const int* __restrict__ cnt, int* __restrict__ offs) {
    if (threadIdx.x == 0) {
        int a = 0;
        for (int e = 0; e < NE; e++) {
            offs[e] = a;
            a += cnt[e];
            a = (a + 255) & ~255;
        }
        offs[NE] = a;   // total padded slots
    }
}

__global__ __launch_bounds__(256) void scatter_kernel(const int2* __restrict__ topidx,
                                                      const float2* __restrict__ topg,
                                                      const int* __restrict__ offs,
                                                      int* __restrict__ fill,
                                                      int* __restrict__ tok,
                                                      float* __restrict__ gate) {
    int t = blockIdx.x * 256 + threadIdx.x;
    if (t >= T_TOKENS) return;
    int2 ix = topidx[t]; float2 g = topg[t];
    int p = atomicAdd(&fill[ix.x], 1);
    int sl = offs[ix.x] + p;
    tok[sl] = t; gate[sl] = g.x;
    p = atomicAdd(&fill[ix.y], 1);
    sl = offs[ix.y] + p;
    tok[sl] = t; gate[sl] = g.y;
}

// ---- merged grouped GEMM, 256x256 tile, BK=64, 8 waves (2M x 4N) -----------
// C[M,N] = A[M,K] * B[N,K]^T, bf16. 1D grid, natural order, n fastest.
// LDS: As/Bs[2 dbuf][2 ks-subtile][256 rows x 32 k] = 128 KB total.
// Within a subtile the verified chunk swizzle: physical chunk = row*4 +
// (kg ^ ((row>>1)&3)) -> ds_read_b128 bank pattern identical to the
// measured-zero-conflict 128² kernel. global_load_lds writes are linear; the
// swizzle is applied on the per-lane GLOBAL source address.
// K-loop (one vmcnt(0) + one barrier per K-tile; 64 MFMA/wave per K-tile):
//   iter j: issue 8 stage loads for K-tile j+1 into buf[c^1] (sealed by the
//   previous barrier) -> ds_read+MFMA K-tile j from buf[c] (setprio around
//   MFMA) -> vmcnt(0) [j+1 landed] -> barrier [buf[c] sealed for overwrite].
// Race audit: writes only ever target the buffer whose last reader crossed
// the previous barrier; vmcnt is per-wave FIFO; barrier is a rendezvous.
// PHASE 1: K=DM,  N=HID; silu -> bf16 into hS (shared) / hE (slots)
// PHASE 2: K=HID, N=DM;  atomicAdd f32 into pre-zeroed out
template<int PHASE>
__global__ __launch_bounds__(512, 2)
void gemm_moe256(const u16* __restrict__ Ash, const u16* __restrict__ Aex,
                 const u16* __restrict__ Bsh, const u16* __restrict__ Bex,
                 const int* __restrict__ offs,
                 const int* __restrict__ tok, const float* __restrict__ gate,
                 u16* __restrict__ hS, u16* __restrict__ hE,
                 float* __restrict__ out) {
    constexpr int KK = (PHASE == 1) ? DM : HID;
    constexpr int NX = (PHASE == 1) ? HID / 256 : DM / 256;
    constexpr long strideB = (long)HID * DM;

    const int wg = blockIdx.x;            // natural order (no swizzle)
    const int n0 = (wg % NX) * 256;
    const int mt = wg / NX;

    const bool sh = (mt < MT_SH2);
    int m0;
    const u16* Ab;
    const u16* B;
    if (sh) {
        m0 = mt * 256;
        Ab = Ash; B = Bsh;
    } else {
        m0 = (mt - MT_SH2) * 256;
        if (m0 >= offs[NE]) return;      // beyond padded total (block-uniform)
        int e = 0;
#pragma unroll
        for (int k = 1; k < NE; k++) e += (m0 >= offs[k]);
        Ab = Aex;
        B = Bex + (long)e * strideB;
    }

    __shared__ u16 As[2][2][256 * 32];   // [dbuf][ks-subtile][row*32 + chunk]
    __shared__ u16 Bs[2][2][256 * 32];

    const int tid  = threadIdx.x;
    const int lane = tid & 63;
    const int wid  = tid >> 6;           // 0..7
    const int wm   = (wid >> 2) * 128;   // wave M offset: 0 / 128
    const int wn   = (wid & 3) * 64;     // wave N offset: 0 / 64 / 128 / 192
    const int lr   = lane & 15;

    // Staging coords: round (h, ks) covers physical chunks p = h*512 + tid of
    // subtile ks. row = h*128 + (tid>>2); swizzled k-chunk invariant across h.
    const int srow = tid >> 2;                        // 0..127
    const int skg  = (tid & 3) ^ ((srow >> 1) & 3);   // same for both halves
    long ar0, ar1;
    if (sh)                      { ar0 = m0 + srow;        ar1 = m0 + srow + 128; }
    else if constexpr (PHASE == 1) { ar0 = tok[m0 + srow];  ar1 = tok[m0 + srow + 128]; }
    else                         { ar0 = m0 + srow;        ar1 = m0 + srow + 128; }
    if constexpr (PHASE == 2) { (void)0; }
    const u16* aP[2] = { Ab + ar0 * (long)KK + skg * 8,
                         Ab + ar1 * (long)KK + skg * 8 };
    const u16* bP[2] = { B + (long)(n0 + srow) * (long)KK + skg * 8,
                         B + (long)(n0 + srow + 128) * (long)KK + skg * 8 };

    // Fragment read offsets (elements within a subtile).
    const int key = (lr >> 1) & 3;
    const int kgx = (lane >> 4) ^ key;
    const int aoe = (wm + lr) * 32 + kgx * 8;
    const int boe = (wn + lr) * 32 + kgx * 8;

    f32x4 acc[8][4];
#pragma unroll
    for (int mi = 0; mi < 8; mi++)
#pragma unroll
        for (int ni = 0; ni < 4; ni++)
            acc[mi][ni] = (f32x4){0.f, 0.f, 0.f, 0.f};

    auto stage = [&](int w, int j) {     // K-tile j -> buffer w (8 loads/thread)
        const long kb = (long)j * 64;
#pragma unroll
        for (int ks = 0; ks < 2; ks++)
#pragma unroll
            for (int h = 0; h < 2; h++) {
                gld16(aP[h] + kb + ks * 32, &As[w][ks][(h * 512 + wid * 64) * 8]);
                gld16(bP[h] + kb + ks * 32, &Bs[w][ks][(h * 512 + wid * 64) * 8]);
            }
    };
    auto compute = [&](int c) {
#pragma unroll
        for (int ks = 0; ks < 2; ks++) {
            const u16* Ac = &As[c][ks][0];
            const u16* Bc = &Bs[c][ks][0];
            short8 af[8], bf[4];
#pragma unroll
            for (int mi = 0; mi < 8; mi++) af[mi] = *(const short8*)&Ac[aoe + mi * 512];
#pragma unroll
            for (int ni = 0; ni < 4; ni++) bf[ni] = *(const short8*)&Bc[boe + ni * 512];
            __builtin_amdgcn_s_setprio(1);
#pragma unroll
            for (int mi = 0; mi < 8; mi++)
#pragma unroll
                for (int ni = 0; ni < 4; ni++)
                    acc[mi][ni] = __builtin_amdgcn_mfma_f32_16x16x32_bf16(
                        af[mi], bf[ni], acc[mi][ni], 0, 0, 0);
            __builtin_amdgcn_s_setprio(0);
        }
    };

    const int nt = KK >> 6;              // K-tiles of 64: 16 (P1) / 64 (P2)

    stage(0, 0);
    asm volatile("s_waitcnt vmcnt(0)" ::: "memory");
    __builtin_amdgcn_s_barrier();
    asm volatile("" ::: "memory");

    for (int j = 0; j < nt; ++j) {
        const int c = j & 1;
        if (j + 1 < nt) stage(c ^ 1, j + 1);   // buf[c^1] sealed by prev barrier
        compute(c);
        asm volatile("s_waitcnt vmcnt(0)" ::: "memory");   // K-tile j+1 landed
        __builtin_amdgcn_s_barrier();                      // buf[c] sealed
        asm volatile("" ::: "memory");
    }

    // Epilogue. C/D layout: col = lane&15, row = (lane>>4)*4 + reg  [m89-verified]
    const int r4 = (lane >> 4) * 4;
    const int cl = lane & 15;
#pragma unroll
    for (int mi = 0; mi < 8; mi++) {
#pragma unroll
        for (int rr = 0; rr < 4; rr++) {
            int row = m0 + wm + mi * 16 + r4 + rr;
            int tt = 0; float g = 0.f;
            if constexpr (PHASE == 2) {
                if (!sh) { tt = tok[row]; g = gate[row]; }
            }
#pragma unroll
            for (int ni = 0; ni < 4; ni++) {
                int col = n0 + wn + ni * 16 + cl;
                float v = acc[mi][ni][rr];
                if constexpr (PHASE == 1) {
                    float s2 = v / (1.f + __expf(-v));
                    if (sh) hS[(long)row * HID + col] = f2b(s2);
                    else    hE[(long)row * HID + col] = f2b(s2);
                } else {
                    if (sh) atomicAdd(&out[(long)row * DM + col], v);
                    else    atomicAdd(&out[(long)tt * DM + col], g * v);
                }
            }
        }
    }
}

// ---- fallback sync GEMM (fp32 B in-flight convert) for small-ws case -------
template<typename TB, int MODE>
__global__ __launch_bounds__(256)
void gemm_bt(const u16* __restrict__ A, int lda,
             const TB* __restrict__ Bbase, int ldb, long strideB, int K,
             int Mstatic,
             const int* __restrict__ cnt, const int* __restrict__ offs,
             const int* __restrict__ tok_of_slot, const float* __restrict__ gate_of_slot,
             u16* __restrict__ Cb, int ldcb,
             float* __restrict__ Cf, int ldcf) {
    int M = Mstatic, base = 0;
    const TB* B = Bbase;
    if constexpr (MODE >= 2) {
        int e = blockIdx.z;
        base = offs[e];
        M = cnt[e];
        B = Bbase + (long)e * strideB;
    }
    const int m0 = blockIdx.y * 128;
    if (m0 >= M) return;
    const int n0 = blockIdx.x * 128;

    __shared__ u16 As[128][40];
    __shared__ u16 Bs[128][40];

    const int tid  = threadIdx.x;
    const int lane = tid & 63;
    const int wid  = tid >> 6;
    const int wm   = (wid >> 1) * 64;
    const int wn   = (wid & 1) * 64;
    const int lr   = lane & 15;
    const int lk   = (lane >> 4) * 8;

    int arow_r[2], akc[2];
    long aoff[2], boff[2];
#pragma unroll
    for (int i = 0; i < 2; i++) {
        int c = tid + i * 256;
        int r = c >> 2, kc = (c & 3) * 8;
        arow_r[i] = r; akc[i] = kc;
        int rr = m0 + r;
        if (rr >= M) rr = M - 1;
        long grow;
        if constexpr (MODE == 2)      grow = tok_of_slot[base + rr];
        else if constexpr (MODE == 3) grow = (long)(base + rr);
        else                          grow = rr;
        aoff[i] = grow * (long)lda + kc;
        boff[i] = (long)(n0 + r) * ldb + kc;
    }

    f32x4 acc[4][4];
#pragma unroll
    for (int mi = 0; mi < 4; mi++)
#pragma unroll
        for (int ni = 0; ni < 4; ni++)
            acc[mi][ni] = (f32x4){0.f, 0.f, 0.f, 0.f};

    for (int k0 = 0; k0 < K; k0 += 32) {
#pragma unroll
        for (int i = 0; i < 2; i++) {
            *(uint4*)&As[arow_r[i]][akc[i]] = load8(A + aoff[i] + k0);
            *(uint4*)&Bs[arow_r[i]][akc[i]] = load8(B + boff[i] + k0);
        }
        __syncthreads();
        short8 af[4], bfr[4];
#pragma unroll
        for (int mi = 0; mi < 4; mi++) af[mi]  = *(const short8*)&As[wm + mi * 16 + lr][lk];
#pragma unroll
        for (int ni = 0; ni < 4; ni++) bfr[ni] = *(const short8*)&Bs[wn + ni * 16 + lr][lk];
#pragma unroll
        for (int mi = 0; mi < 4; mi++)
#pragma unroll
            for (int ni = 0; ni < 4; ni++)
                acc[mi][ni] = __builtin_amdgcn_mfma_f32_16x16x32_bf16(af[mi], bfr[ni],
                                                                      acc[mi][ni], 0, 0, 0);
        __syncthreads();
    }

    const int r4 = (lane >> 4) * 4;
    const int cl = lane & 15;
#pragma unroll
    for (int mi = 0; mi < 4; mi++) {
#pragma unroll
        for (int rr = 0; rr < 4; rr++) {
            int row = m0 + wm + mi * 16 + r4 + rr;
            if constexpr (MODE >= 2) { if (row >= M) continue; }
            int t = 0; float g = 0.f;
            if constexpr (MODE == 3) {
                t = tok_of_slot[base + row];
                g = gate_of_slot[base + row];
            }
#pragma unroll
            for (int ni = 0; ni < 4; ni++) {
                int col = n0 + wn + ni * 16 + cl;
                float v = acc[mi][ni][rr];
                if constexpr (MODE == 2) {
                    float s = v / (1.f + __expf(-v));
                    Cb[(long)(base + row) * ldcb + col] = f2b(s);
                } else if constexpr (MODE == 3) {
                    atomicAdd(&Cf[(long)t * ldcf + col], g * v);
                }
            }
        }
    }
}

extern "C" void kernel_launch(void* const* d_in, const int* in_sizes, int n_in,
                              void* d_out, int out_size, void* d_ws, size_t ws_size,
                              hipStream_t stream) {
    const float* x   = (const float*)d_in[0];
    const float* sw1 = (const float*)d_in[1];
    const float* sw2 = (const float*)d_in[2];
    const float* ew1 = (const float*)d_in[3];
    const float* ew2 = (const float*)d_in[4];
    const float* gw  = (const float*)d_in[5];
    float* out = (float*)d_out;

    char* ws = (char*)d_ws;
    size_t off = 0;
    auto alloc = [&](size_t bytes) -> char* {
        off = (off + 255) & ~(size_t)255;
        char* p = ws + off;
        off += bytes;
        return p;
    };

    int*    meta   = (int*)alloc(256);          // cnt[8] | fill[8] | offs[9]
    int*    cnt    = meta;
    int*    fill   = meta + 8;
    int*    offs   = meta + 16;
    int2*   topidx = (int2*)alloc((size_t)T_TOKENS * 8);
    float2* topg   = (float2*)alloc((size_t)T_TOKENS * 8);
    int*    tok    = (int*)alloc((size_t)SLOTS_MAX * 4);
    float*  gate   = (float*)alloc((size_t)SLOTS_MAX * 4);
    u16* xb   = (u16*)alloc((size_t)T_TOKENS * DM * 2);
    u16* sw1b = (u16*)alloc((size_t)HID * DM * 2);
    u16* sw2b = (u16*)alloc((size_t)DM * HID * 2);
    u16* hidS = (u16*)alloc((size_t)T_TOKENS * HID * 2);
    u16* hidE = (u16*)alloc((size_t)SLOTS_MAX * HID * 2);

    const size_t ew_bytes = (size_t)NE * HID * DM * 2;   // 64 MB each
    bool cvt_ew = (ws_size >= off + 2 * ew_bytes + 1024);
    u16 *ew1b = nullptr, *ew2b = nullptr;
    if (cvt_ew) {
        ew1b = (u16*)alloc(ew_bytes);
        ew2b = (u16*)alloc(ew_bytes);
    }

    hipMemsetAsync(meta, 0, 64, stream);                         // cnt+fill
    hipMemsetAsync(tok, 0, (size_t)SLOTS_MAX * 4, stream);       // padding -> token 0
    hipMemsetAsync(gate, 0, (size_t)SLOTS_MAX * 4, stream);      // padding -> gate 0
    hipMemsetAsync(out, 0, (size_t)T_TOKENS * DM * 4, stream);   // L2 is all-atomicAdd

    if (cvt_ew)
        cvt_all_kernel<true><<<(int)(CN4 / 2048), 256, 0, stream>>>(
            x, sw1, sw2, ew1, ew2, xb, sw1b, sw2b, ew1b, ew2b);
    else
        cvt_all_kernel<false><<<(int)(CN2 / 2048), 256, 0, stream>>>(
            x, sw1, sw2, nullptr, nullptr, xb, sw1b, sw2b, nullptr, nullptr);

    gate_kernel<<<T_TOKENS / 4, 256, 0, stream>>>(x, gw, cnt, topidx, topg);
    prefix_kernel<<<1, 64, 0, stream>>>(cnt, offs);
    scatter_kernel<<<T_TOKENS / 256, 256, 0, stream>>>(topidx, topg, offs, fill, tok, gate);

    dim3 blk(512);
    if (cvt_ew) {
        // L1 merged: shared (16 m-tiles) + experts (<=40 padded m-tiles), N=HID
        gemm_moe256<1><<<dim3((MT_SH2 + MT_EX2) * (HID / 256)), blk, 0, stream>>>(
            xb, xb, sw1b, ew1b, offs, tok, gate, hidS, hidE, nullptr);
        // L2 merged: N=DM, all-atomicAdd into pre-zeroed out
        gemm_moe256<2><<<dim3((MT_SH2 + MT_EX2) * (DM / 256)), blk, 0, stream>>>(
            hidS, hidE, sw2b, ew2b, offs, tok, gate, nullptr, nullptr, out);
    } else {
        // shared-only via gemm_moe256 (grid limited to shared section),
        // experts via in-flight-convert fallback (real slot counts only).
        gemm_moe256<1><<<dim3(MT_SH2 * (HID / 256)), blk, 0, stream>>>(
            xb, xb, sw1b, nullptr, offs, tok, gate, hidS, nullptr, nullptr);
        gemm_bt<float, 2><<<dim3(HID / 128, T_TOKENS / 128, NE), dim3(256), 0, stream>>>(
            xb, DM, ew1, DM, (long)HID * DM, DM, 0,
            cnt, offs, tok, gate, hidE, HID, nullptr, 0);
        gemm_moe256<2><<<dim3(MT_SH2 * (DM / 256)), blk, 0, stream>>>(
            hidS, hidE, sw2b, nullptr, offs, tok, gate, nullptr, nullptr, out);
        gemm_bt<float, 3><<<dim3(DM / 128, T_TOKENS / 128, NE), dim3(256), 0, stream>>>(
            hidE, HID, ew2, HID, (long)DM * HID, HID, 0,
            cnt, offs, tok, gate, nullptr, 0, out, DM);
    }
}